// Round 5
// baseline (227.618 us; speedup 1.0000x reference)
//
#include <hip/hip_runtime.h>
#include <hip/hip_bf16.h>

// DeConv2d = 32 per-channel MLPs (128->256->256->4) over 8192 px + 2x2 shuffle.
//
// R5: R4 was LDS-read-bound (nf=2 -> each 16B B-frag feeds only 2 MFMAs;
// 33us LDS floor) plus under-pipelined. Changes:
//  - 256-thread blocks, 4 waves, each wave owns 64 n (nf=4): LDS reads halve
//  - W1/W2 STREAMED from L2 with 3-buffer rotation (dist-3 prefetch ~300cy);
//    only W3 resident (nf=4-resident W1+W2 would blow VGPR budget)
//  - L3 per-wave-full-K (wave w owns 16 px): no partial exchange, 4 barriers/tile
//  - B-fragments (LDS) stay 1-step double-buffered
//
// Workspace: pix [8192][128] bf16 @0; W1t [32][256][128] @2MB; W2t [32][256][256] @4MB;
//            W3t [32][16][256] @8MB (rows 4..15 zero).

#define IC    128
#define IHW   1024
#define OCH   32
#define HDIM  256

typedef float  f32x4  __attribute__((ext_vector_type(4)));
typedef float  f32x2  __attribute__((ext_vector_type(2)));
typedef __bf16 bf16x8 __attribute__((ext_vector_type(8)));
typedef unsigned short us8 __attribute__((ext_vector_type(8)));
typedef unsigned int u32;

static __device__ __forceinline__ unsigned short f2bf(float f) {
  __hip_bfloat16 h = __float2bfloat16(f);
  return __builtin_bit_cast(unsigned short, h);
}

static __device__ __forceinline__ bf16x8 ld16(const unsigned short* p) {
  return __builtin_bit_cast(bf16x8, *reinterpret_cast<const uint4*>(p));
}

static __device__ __forceinline__ void gl_lds16(const unsigned short* g, char* l) {
  __builtin_amdgcn_global_load_lds(
      (const __attribute__((address_space(1))) u32*)g,
      (__attribute__((address_space(3))) u32*)l,
      16, 0, 0);
}

// ---- coalesced transpose prepass: dst[b][c][r] (bf16) = src[b][r][c] (f32) ----
__global__ __launch_bounds__(256) void transpose_bf16_k(
    const float* __restrict__ src, unsigned short* __restrict__ dst,
    int NR, int NC, int nrt, int nct)
{
  __shared__ float tl[64 * 65];
  const int bid = blockIdx.x;
  const int ct = bid % nct;
  const int rt = (bid / nct) % nrt;
  const int b  = bid / (nct * nrt);
  const int t  = threadIdx.x;

  const float* sb = src + ((size_t)b * NR + (rt << 6)) * NC + (ct << 6);
  const int col = (t & 15) << 2;
  const int rq  = t >> 4;
#pragma unroll
  for (int rr = 0; rr < 4; ++rr) {
    int row = (rr << 4) + rq;
    f32x4 v = *reinterpret_cast<const f32x4*>(sb + row * NC + col);
#pragma unroll
    for (int i = 0; i < 4; ++i) tl[row * 65 + col + i] = v[i];
  }
  __syncthreads();

  unsigned short* db = dst + ((size_t)b * NC + (ct << 6)) * NR + (rt << 6);
  const int r0 = (t & 7) << 3;
  const int cq = t >> 3;
#pragma unroll
  for (int cr = 0; cr < 2; ++cr) {
    int c = (cr << 5) + cq;
    us8 vv;
#pragma unroll
    for (int i = 0; i < 8; ++i) vv[i] = f2bf(tl[(r0 + i) * 65 + c]);
    *reinterpret_cast<us8*>(db + (size_t)c * NR + r0) = vv;
  }
}

__global__ void conv_w3_k(const float* __restrict__ W3, unsigned short* __restrict__ W3t) {
  int idx = blockIdx.x * 256 + threadIdx.x;
  int k = idx & 255;
  int nn = (idx >> 8) & 15;
  int o = idx >> 12;
  W3t[idx] = (nn < 4) ? f2bf(W3[(o * HDIM + k) * 4 + nn]) : (unsigned short)0;
}

// ---- fused 3-layer MLP ----
// Block = 256 thr = 4 waves, (group o, 256 px as 4 tiles of 64).
// Wave w owns n-rows [w*64, w*64+64) for layers 1-2 (nf=4).
// D frag: col=lane&15 -> px, row=(lane>>4)*4+reg -> n.
// LDS: pix dbuf 2x16KB @0; h 32KB @32768. Swizzle ^((m&7)<<4).

#define LD_B_PIX(dst, ks)                                                        \
  _Pragma("unroll")                                                              \
  for (int mf = 0; mf < 4; ++mf) {                                               \
    int m = (mf << 4) + l15;                                                     \
    dst[mf] = *reinterpret_cast<const bf16x8*>(                                  \
        pb + ((((m << 8) + ((ks) << 6) + (kgrp << 1))) ^ ((m & 7) << 4)));       \
  }

#define LD_B_H(dst, ks)                                                          \
  _Pragma("unroll")                                                              \
  for (int mf = 0; mf < 4; ++mf) {                                               \
    int m = (mf << 4) + l15;                                                     \
    dst[mf] = *reinterpret_cast<const bf16x8*>(                                  \
        hb + ((((m << 9) + ((ks) << 6) + (kgrp << 1))) ^ ((m & 7) << 4)));       \
  }

#define LD_W1(dst, ks)                                                           \
  _Pragma("unroll")                                                              \
  for (int nf = 0; nf < 4; ++nf) dst[nf] = ld16(W1p + (nf << 4) * IC + ((ks) << 5));

#define LD_W2(dst, ks)                                                           \
  _Pragma("unroll")                                                              \
  for (int nf = 0; nf < 4; ++nf) dst[nf] = ld16(W2p + (nf << 4) * HDIM + ((ks) << 5));

#define MFMA16(WV, BP)                                                           \
  _Pragma("unroll")                                                              \
  for (int nf = 0; nf < 4; ++nf)                                                 \
    _Pragma("unroll")                                                            \
    for (int mf = 0; mf < 4; ++mf)                                               \
      acc[nf][mf] = __builtin_amdgcn_mfma_f32_16x16x32_bf16(WV[nf], BP[mf], acc[nf][mf], 0, 0, 0);

#define EPILOGUE(bias, region)                                                   \
  _Pragma("unroll")                                                              \
  for (int nf = 0; nf < 4; ++nf) {                                               \
    int n0 = wnb + (nf << 4) + (lg << 2);                                        \
    f32x4 bb = *reinterpret_cast<const f32x4*>((bias) + n0);                     \
    _Pragma("unroll")                                                            \
    for (int mf = 0; mf < 4; ++mf) {                                             \
      int m = (mf << 4) + l15;                                                   \
      ushort4 hv;                                                                \
      hv.x = f2bf(fmaxf(acc[nf][mf][0] + bb[0], 0.f));                           \
      hv.y = f2bf(fmaxf(acc[nf][mf][1] + bb[1], 0.f));                           \
      hv.z = f2bf(fmaxf(acc[nf][mf][2] + bb[2], 0.f));                           \
      hv.w = f2bf(fmaxf(acc[nf][mf][3] + bb[3], 0.f));                           \
      *reinterpret_cast<ushort4*>(                                               \
          (region) + (((m << 9) + (n0 << 1)) ^ ((m & 7) << 4))) = hv;            \
    }                                                                            \
  }

__global__ __launch_bounds__(256, 2) void fused_mlp_k(
    const unsigned short* __restrict__ pix,
    const unsigned short* __restrict__ W1t,
    const unsigned short* __restrict__ W2t,
    const unsigned short* __restrict__ W3t,
    const float* __restrict__ b1,
    const float* __restrict__ b2,
    const float* __restrict__ b3f,
    float* __restrict__ out)
{
  __shared__ __align__(16) char lds[65536];
  const int t    = threadIdx.x;
  const int lane = t & 63;
  const int w    = t >> 6;                          // 0..3
  const int bx   = blockIdx.x;
  const int o    = ((bx & 7) << 2) | ((bx >> 3) & 3);
  const int pixbase = (bx >> 5) << 8;               // 256 px per block

  const int l15  = lane & 15;
  const int lg   = lane >> 4;
  const int kgrp = lg << 3;
  const int wnb  = w << 6;                          // wave's n-base (64 rows)

  // ---- pix tile 0 prefetch (longest latency first) ----
#pragma unroll
  for (int r = 0; r < 4; ++r) {
    int slot = (r << 8) + t;
    int m = slot >> 4, j = slot & 15;
    gl_lds16(pix + (size_t)(pixbase + m) * IC + ((j ^ (m & 7)) << 3),
             lds + (((r << 8) + (w << 6)) << 4));
  }

  // ---- W3 resident (8 frags, 32 VGPR) ----
  bf16x8 W3r[8];
#pragma unroll
  for (int ks = 0; ks < 8; ++ks)
    W3r[ks] = ld16(W3t + (o << 12) + l15 * HDIM + (ks << 5) + kgrp);

  const unsigned short* W1p = W1t + (o << 15) + (wnb + l15) * IC + kgrp;
  const unsigned short* W2p = W2t + (o << 16) + (wnb + l15) * HDIM + kgrp;
  const float* b1o = b1 + (o << 8);
  const float* b2o = b2 + (o << 8);
  const f32x4 vzero = {0.f, 0.f, 0.f, 0.f};

  __syncthreads();   // pix tile 0 ready

  for (int tt = 0; tt < 4; ++tt) {
    const int cur = tt & 1;
    char* pb = lds + (cur << 14);
    char* hb = lds + 32768;

    // issue next tile's pix loads (drain at B1)
    if (tt < 3) {
      char* nb = lds + ((cur ^ 1) << 14);
#pragma unroll
      for (int r = 0; r < 4; ++r) {
        int slot = (r << 8) + t;
        int m = slot >> 4, j = slot & 15;
        gl_lds16(pix + (size_t)(pixbase + ((tt + 1) << 6) + m) * IC + ((j ^ (m & 7)) << 3),
                 nb + (((r << 8) + (w << 6)) << 4));
      }
    }

    f32x4 acc[4][4];
#pragma unroll
    for (int nf = 0; nf < 4; ++nf)
#pragma unroll
      for (int mf = 0; mf < 4; ++mf) acc[nf][mf] = vzero;

    bf16x8 wv0[4], wv1[4], wv2[4], bp[4], bq[4];

    // ================= layer 1: K=128 (4 ks), W1 streamed 3-buf =================
    LD_W1(wv0, 0) LD_W1(wv1, 1) LD_W1(wv2, 2)
    LD_B_PIX(bp, 0)
    LD_B_PIX(bq, 1) MFMA16(wv0, bp) LD_W1(wv0, 3)
    LD_B_PIX(bp, 2) MFMA16(wv1, bq)
    LD_B_PIX(bq, 3) MFMA16(wv2, bp)
    MFMA16(wv0, bq)

    EPILOGUE(b1o, hb)
    __syncthreads();   // B1: h1 visible (+ pix tt+1 drained)

    // ================= layer 2: K=256 (8 ks), W2 streamed 3-buf =================
#pragma unroll
    for (int nf = 0; nf < 4; ++nf)
#pragma unroll
      for (int mf = 0; mf < 4; ++mf) acc[nf][mf] = vzero;

    LD_W2(wv0, 0) LD_W2(wv1, 1) LD_W2(wv2, 2)
    LD_B_H(bp, 0)
    LD_B_H(bq, 1) MFMA16(wv0, bp) LD_W2(wv0, 3)
    LD_B_H(bp, 2) MFMA16(wv1, bq) LD_W2(wv1, 4)
    LD_B_H(bq, 3) MFMA16(wv2, bp) LD_W2(wv2, 5)
    LD_B_H(bp, 4) MFMA16(wv0, bq) LD_W2(wv0, 6)
    LD_B_H(bq, 5) MFMA16(wv1, bp) LD_W2(wv1, 7)
    LD_B_H(bp, 6) MFMA16(wv2, bq)
    LD_B_H(bq, 7) MFMA16(wv0, bp)
    MFMA16(wv1, bq)

    __syncthreads();   // B2: all h1 reads done

    EPILOGUE(b2o, hb)  // h2 overwrites h1 region
    __syncthreads();   // B3: h2 visible

    // ================= layer 3: wave w owns px [w*16, w*16+16), full K ==========
    f32x4 acc3 = vzero;
    {
      const int m3 = (w << 4) + l15;
      bf16x8 bh = *reinterpret_cast<const bf16x8*>(
          hb + (((m3 << 9) + (kgrp << 1)) ^ ((m3 & 7) << 4)));
#pragma unroll
      for (int ks = 0; ks < 8; ++ks) {
        bf16x8 bn;
        if (ks < 7)
          bn = *reinterpret_cast<const bf16x8*>(
              hb + (((m3 << 9) + ((ks + 1) << 6) + (kgrp << 1)) ^ ((m3 & 7) << 4)));
        acc3 = __builtin_amdgcn_mfma_f32_16x16x32_bf16(W3r[ks], bh, acc3, 0, 0, 0);
        bh = bn;
      }
      // rows 0..3 (outputs) live in lanes 0..15
      if (lane < 16) {
        int pixel = pixbase + (tt << 6) + m3;
        int n = pixel >> 10, p = pixel & 1023;
        int ii = p >> 5, jj = p & 31;
        float* ob = out + ((size_t)((n << 5) + o) << 12) + (ii << 7) + (jj << 1);
        f32x2 r0 = { acc3[0] + b3f[(o << 2) + 0], acc3[1] + b3f[(o << 2) + 1] };
        f32x2 r1 = { acc3[2] + b3f[(o << 2) + 2], acc3[3] + b3f[(o << 2) + 3] };
        *reinterpret_cast<f32x2*>(ob) = r0;
        *reinterpret_cast<f32x2*>(ob + 64) = r1;
      }
    }
    __syncthreads();   // B4: h2 reads done; next tile may overwrite hb
  }
}

extern "C" void kernel_launch(void* const* d_in, const int* in_sizes, int n_in,
                              void* d_out, int out_size, void* d_ws, size_t ws_size,
                              hipStream_t stream) {
  const float* x  = (const float*)d_in[0];
  const float* W1 = (const float*)d_in[1];
  const float* b1 = (const float*)d_in[2];
  const float* W2 = (const float*)d_in[3];
  const float* b2 = (const float*)d_in[4];
  const float* W3 = (const float*)d_in[5];
  const float* b3 = (const float*)d_in[6];
  float* out = (float*)d_out;

  char* ws = (char*)d_ws;
  unsigned short* pixw = (unsigned short*)(ws);
  unsigned short* W1t  = (unsigned short*)(ws + (size_t)(2u << 20));
  unsigned short* W2t  = (unsigned short*)(ws + (size_t)(4u << 20));
  unsigned short* W3t  = (unsigned short*)(ws + (size_t)(8u << 20));

  transpose_bf16_k<<<8 * 2 * 16, 256, 0, stream>>>(x, pixw, 128, 1024, 2, 16);
  transpose_bf16_k<<<32 * 2 * 4, 256, 0, stream>>>(W1, W1t, 128, 256, 2, 4);
  transpose_bf16_k<<<32 * 4 * 4, 256, 0, stream>>>(W2, W2t, 256, 256, 4, 4);
  conv_w3_k<<<512, 256, 0, stream>>>(W3, W3t);

  fused_mlp_k<<<1024, 256, 0, stream>>>(pixw, W1t, W2t, W3t, b1, b2, b3, out);
}

// Round 6
// 130.226 us; speedup vs baseline: 1.7479x; 1.7479x over previous
//
#include <hip/hip_runtime.h>
#include <hip/hip_bf16.h>

// DeConv2d = 32 per-channel MLPs (128->256->256->4) over 8192 px + 2x2 shuffle.
//
// R6: R5's nf=4 structure spilled (WRITE_SIZE 183MB = scratch). Keep nf=4
// (LDS-read floor ~18us < MFMA floor ~26us), cut register demand:
//  - 2-buffer weight streaming (not 3): wv 48->32 VGPR
//  - W3 NOT resident: loaded per-tile in L3 after acc[][] dies
//  - 1 tile/block (grid 4096): pix single-buffered, LDS 48KB -> 3 blocks/CU,
//    4 barriers/block; weight loads issued before the pix barrier
// Peak live ~152 VGPR (vs R5's ~196 over the 128 cliff).
//
// Workspace: pix [8192][128] bf16 @0; W1t [32][256][128] @2MB; W2t [32][256][256] @4MB;
//            W3t [32][16][256] @8MB (rows 4..15 zero).

#define IC    128
#define IHW   1024
#define OCH   32
#define HDIM  256

typedef float  f32x4  __attribute__((ext_vector_type(4)));
typedef float  f32x2  __attribute__((ext_vector_type(2)));
typedef __bf16 bf16x8 __attribute__((ext_vector_type(8)));
typedef unsigned short us8 __attribute__((ext_vector_type(8)));
typedef unsigned int u32;

static __device__ __forceinline__ unsigned short f2bf(float f) {
  __hip_bfloat16 h = __float2bfloat16(f);
  return __builtin_bit_cast(unsigned short, h);
}

static __device__ __forceinline__ bf16x8 ld16(const unsigned short* p) {
  return __builtin_bit_cast(bf16x8, *reinterpret_cast<const uint4*>(p));
}

static __device__ __forceinline__ void gl_lds16(const unsigned short* g, char* l) {
  __builtin_amdgcn_global_load_lds(
      (const __attribute__((address_space(1))) u32*)g,
      (__attribute__((address_space(3))) u32*)l,
      16, 0, 0);
}

// ---- coalesced transpose prepass: dst[b][c][r] (bf16) = src[b][r][c] (f32) ----
__global__ __launch_bounds__(256) void transpose_bf16_k(
    const float* __restrict__ src, unsigned short* __restrict__ dst,
    int NR, int NC, int nrt, int nct)
{
  __shared__ float tl[64 * 65];
  const int bid = blockIdx.x;
  const int ct = bid % nct;
  const int rt = (bid / nct) % nrt;
  const int b  = bid / (nct * nrt);
  const int t  = threadIdx.x;

  const float* sb = src + ((size_t)b * NR + (rt << 6)) * NC + (ct << 6);
  const int col = (t & 15) << 2;
  const int rq  = t >> 4;
#pragma unroll
  for (int rr = 0; rr < 4; ++rr) {
    int row = (rr << 4) + rq;
    f32x4 v = *reinterpret_cast<const f32x4*>(sb + row * NC + col);
#pragma unroll
    for (int i = 0; i < 4; ++i) tl[row * 65 + col + i] = v[i];
  }
  __syncthreads();

  unsigned short* db = dst + ((size_t)b * NC + (ct << 6)) * NR + (rt << 6);
  const int r0 = (t & 7) << 3;
  const int cq = t >> 3;
#pragma unroll
  for (int cr = 0; cr < 2; ++cr) {
    int c = (cr << 5) + cq;
    us8 vv;
#pragma unroll
    for (int i = 0; i < 8; ++i) vv[i] = f2bf(tl[(r0 + i) * 65 + c]);
    *reinterpret_cast<us8*>(db + (size_t)c * NR + r0) = vv;
  }
}

__global__ void conv_w3_k(const float* __restrict__ W3, unsigned short* __restrict__ W3t) {
  int idx = blockIdx.x * 256 + threadIdx.x;
  int k = idx & 255;
  int nn = (idx >> 8) & 15;
  int o = idx >> 12;
  W3t[idx] = (nn < 4) ? f2bf(W3[(o * HDIM + k) * 4 + nn]) : (unsigned short)0;
}

// ---- fused 3-layer MLP ----
// Block = 256 thr = 4 waves, (group o, one 64-px tile). Wave w owns n-rows
// [w*64, w*64+64) for layers 1-2 (nf=4). D frag: col=lane&15 -> px,
// row=(lane>>4)*4+reg -> n. LDS: pix 16KB @0; h 32KB @16384. Swizzle ^((m&7)<<4).

#define LD_B_PIX(dst, ks)                                                        \
  _Pragma("unroll")                                                              \
  for (int mf = 0; mf < 4; ++mf) {                                               \
    int m = (mf << 4) + l15;                                                     \
    dst[mf] = *reinterpret_cast<const bf16x8*>(                                  \
        pb + ((((m << 8) + ((ks) << 6) + (kgrp << 1))) ^ ((m & 7) << 4)));       \
  }

#define LD_B_H(dst, ks)                                                          \
  _Pragma("unroll")                                                              \
  for (int mf = 0; mf < 4; ++mf) {                                               \
    int m = (mf << 4) + l15;                                                     \
    dst[mf] = *reinterpret_cast<const bf16x8*>(                                  \
        hb + ((((m << 9) + ((ks) << 6) + (kgrp << 1))) ^ ((m & 7) << 4)));       \
  }

#define LD_W1(dst, ks)                                                           \
  _Pragma("unroll")                                                              \
  for (int nf = 0; nf < 4; ++nf) dst[nf] = ld16(W1p + (nf << 4) * IC + ((ks) << 5));

#define LD_W2(dst, ks)                                                           \
  _Pragma("unroll")                                                              \
  for (int nf = 0; nf < 4; ++nf) dst[nf] = ld16(W2p + (nf << 4) * HDIM + ((ks) << 5));

#define MFMA16(WV, BP)                                                           \
  _Pragma("unroll")                                                              \
  for (int nf = 0; nf < 4; ++nf)                                                 \
    _Pragma("unroll")                                                            \
    for (int mf = 0; mf < 4; ++mf)                                               \
      acc[nf][mf] = __builtin_amdgcn_mfma_f32_16x16x32_bf16(WV[nf], BP[mf], acc[nf][mf], 0, 0, 0);

#define EPILOGUE(bias, region)                                                   \
  _Pragma("unroll")                                                              \
  for (int nf = 0; nf < 4; ++nf) {                                               \
    int n0 = wnb + (nf << 4) + (lg << 2);                                        \
    f32x4 bb = *reinterpret_cast<const f32x4*>((bias) + n0);                     \
    _Pragma("unroll")                                                            \
    for (int mf = 0; mf < 4; ++mf) {                                             \
      int m = (mf << 4) + l15;                                                   \
      ushort4 hv;                                                                \
      hv.x = f2bf(fmaxf(acc[nf][mf][0] + bb[0], 0.f));                           \
      hv.y = f2bf(fmaxf(acc[nf][mf][1] + bb[1], 0.f));                           \
      hv.z = f2bf(fmaxf(acc[nf][mf][2] + bb[2], 0.f));                           \
      hv.w = f2bf(fmaxf(acc[nf][mf][3] + bb[3], 0.f));                           \
      *reinterpret_cast<ushort4*>(                                               \
          (region) + (((m << 9) + (n0 << 1)) ^ ((m & 7) << 4))) = hv;            \
    }                                                                            \
  }

__global__ __launch_bounds__(256, 3) void fused_mlp_k(
    const unsigned short* __restrict__ pix,
    const unsigned short* __restrict__ W1t,
    const unsigned short* __restrict__ W2t,
    const unsigned short* __restrict__ W3t,
    const float* __restrict__ b1,
    const float* __restrict__ b2,
    const float* __restrict__ b3f,
    float* __restrict__ out)
{
  __shared__ __align__(16) char lds[49152];
  const int t    = threadIdx.x;
  const int lane = t & 63;
  const int w    = t >> 6;                          // 0..3
  const int bx   = blockIdx.x;
  const int o    = ((bx & 7) << 2) | ((bx >> 3) & 3);
  const int m0   = (bx >> 5) << 6;                  // 64 px per block

  const int l15  = lane & 15;
  const int lg   = lane >> 4;
  const int kgrp = lg << 3;
  const int wnb  = w << 6;

  char* pb = lds;
  char* hb = lds + 16384;

  // ---- issue pix stage (async, drains at first barrier) ----
#pragma unroll
  for (int r = 0; r < 4; ++r) {
    int slot = (r << 8) + t;
    int m = slot >> 4, j = slot & 15;
    gl_lds16(pix + (size_t)(m0 + m) * IC + ((j ^ (m & 7)) << 3),
             pb + (((r << 8) + (w << 6)) << 4));
  }

  const unsigned short* W1p = W1t + (o << 15) + (wnb + l15) * IC + kgrp;
  const unsigned short* W2p = W2t + (o << 16) + (wnb + l15) * HDIM + kgrp;
  const float* b1o = b1 + (o << 8);
  const float* b2o = b2 + (o << 8);
  const f32x4 vzero = {0.f, 0.f, 0.f, 0.f};

  bf16x8 wv0[4], wv1[4], bp[4], bq[4];
  LD_W1(wv0, 0) LD_W1(wv1, 1)          // issued before the barrier (L2-hot)

  f32x4 acc[4][4];
#pragma unroll
  for (int nf = 0; nf < 4; ++nf)
#pragma unroll
    for (int mf = 0; mf < 4; ++mf) acc[nf][mf] = vzero;

  __syncthreads();   // pix tile ready

  // ================= layer 1: K=128 (4 ks), W1 2-buf streamed ================
  LD_B_PIX(bp, 0)
  LD_B_PIX(bq, 1) MFMA16(wv0, bp) LD_W1(wv0, 2)
  LD_B_PIX(bp, 2) MFMA16(wv1, bq) LD_W1(wv1, 3)
  LD_B_PIX(bq, 3) MFMA16(wv0, bp) LD_W2(wv0, 0)   // W2 ks0 into dead wv0
  MFMA16(wv1, bq) LD_W2(wv1, 1)                   // W2 ks1 into dead wv1

  EPILOGUE(b1o, hb)
  __syncthreads();   // B1: h1 visible

  // ================= layer 2: K=256 (8 ks), W2 2-buf streamed ================
#pragma unroll
  for (int nf = 0; nf < 4; ++nf)
#pragma unroll
    for (int mf = 0; mf < 4; ++mf) acc[nf][mf] = vzero;

  LD_B_H(bp, 0)
  LD_B_H(bq, 1) MFMA16(wv0, bp) LD_W2(wv0, 2)
  LD_B_H(bp, 2) MFMA16(wv1, bq) LD_W2(wv1, 3)
  LD_B_H(bq, 3) MFMA16(wv0, bp) LD_W2(wv0, 4)
  LD_B_H(bp, 4) MFMA16(wv1, bq) LD_W2(wv1, 5)
  LD_B_H(bq, 5) MFMA16(wv0, bp) LD_W2(wv0, 6)
  LD_B_H(bp, 6) MFMA16(wv1, bq) LD_W2(wv1, 7)
  LD_B_H(bq, 7) MFMA16(wv0, bp)
  MFMA16(wv1, bq)

  __syncthreads();   // B2: all h1 reads done

  EPILOGUE(b2o, hb)  // h2 overwrites h1 region
  __syncthreads();   // B3: h2 visible

  // ================= layer 3: wave w owns px [w*16, w*16+16), full K =========
  {
    f32x4 acc3 = vzero;
    const unsigned short* W3p = W3t + (o << 12) + l15 * HDIM + kgrp;
    const int m3 = (w << 4) + l15;
    bf16x8 w3c = ld16(W3p);
    bf16x8 bh = *reinterpret_cast<const bf16x8*>(
        hb + (((m3 << 9) + (kgrp << 1)) ^ ((m3 & 7) << 4)));
#pragma unroll
    for (int ks = 0; ks < 8; ++ks) {
      bf16x8 w3n, bn;
      if (ks < 7) {
        w3n = ld16(W3p + ((ks + 1) << 5));
        bn = *reinterpret_cast<const bf16x8*>(
            hb + (((m3 << 9) + ((ks + 1) << 6) + (kgrp << 1)) ^ ((m3 & 7) << 4)));
      }
      acc3 = __builtin_amdgcn_mfma_f32_16x16x32_bf16(w3c, bh, acc3, 0, 0, 0);
      w3c = w3n; bh = bn;
    }
    // rows 0..3 (outputs) live in lanes 0..15
    if (lane < 16) {
      int pixel = m0 + m3;
      int n = pixel >> 10, p = pixel & 1023;
      int ii = p >> 5, jj = p & 31;
      float* ob = out + ((size_t)((n << 5) + o) << 12) + (ii << 7) + (jj << 1);
      f32x2 r0 = { acc3[0] + b3f[(o << 2) + 0], acc3[1] + b3f[(o << 2) + 1] };
      f32x2 r1 = { acc3[2] + b3f[(o << 2) + 2], acc3[3] + b3f[(o << 2) + 3] };
      *reinterpret_cast<f32x2*>(ob) = r0;
      *reinterpret_cast<f32x2*>(ob + 64) = r1;
    }
  }
}

extern "C" void kernel_launch(void* const* d_in, const int* in_sizes, int n_in,
                              void* d_out, int out_size, void* d_ws, size_t ws_size,
                              hipStream_t stream) {
  const float* x  = (const float*)d_in[0];
  const float* W1 = (const float*)d_in[1];
  const float* b1 = (const float*)d_in[2];
  const float* W2 = (const float*)d_in[3];
  const float* b2 = (const float*)d_in[4];
  const float* W3 = (const float*)d_in[5];
  const float* b3 = (const float*)d_in[6];
  float* out = (float*)d_out;

  char* ws = (char*)d_ws;
  unsigned short* pixw = (unsigned short*)(ws);
  unsigned short* W1t  = (unsigned short*)(ws + (size_t)(2u << 20));
  unsigned short* W2t  = (unsigned short*)(ws + (size_t)(4u << 20));
  unsigned short* W3t  = (unsigned short*)(ws + (size_t)(8u << 20));

  transpose_bf16_k<<<8 * 2 * 16, 256, 0, stream>>>(x, pixw, 128, 1024, 2, 16);
  transpose_bf16_k<<<32 * 2 * 4, 256, 0, stream>>>(W1, W1t, 128, 256, 2, 4);
  transpose_bf16_k<<<32 * 4 * 4, 256, 0, stream>>>(W2, W2t, 256, 256, 4, 4);
  conv_w3_k<<<512, 256, 0, stream>>>(W3, W3t);

  fused_mlp_k<<<4096, 256, 0, stream>>>(pixw, W1t, W2t, W3t, b1, b2, b3, out);
}